// Round 4
// baseline (1321.730 us; speedup 1.0000x reference)
//
#include <hip/hip_runtime.h>
#include <stdint.h>

#define B_     32
#define IMG    56
#define L_     (IMG*IMG)     // 3136
#define C_     384
#define HEADS_ 12
#define HD     32
#define WS_    7
#define N_     49
#define NWIN   64            // 8x8 windows per image
#define NB     (B_*NWIN)     // 2048
#define M_TOK  (NB*N_)       // 100352
#define QKVF   1152

typedef __attribute__((ext_vector_type(8))) short bf16x8;
typedef __attribute__((ext_vector_type(4))) float f32x4;
typedef __attribute__((ext_vector_type(4))) unsigned short u16x4;

__device__ __forceinline__ float bf2f(unsigned short u) {
  union { unsigned int u; float f; } c; c.u = ((unsigned int)u) << 16; return c.f;
}
__device__ __forceinline__ unsigned short f2bf(float f) {
  union { float f; unsigned int u; } c; c.f = f;
  unsigned int r = c.u + 0x7FFFu + ((c.u >> 16) & 1u);
  return (unsigned short)(r >> 16);
}

// async global->LDS, 16B per lane. LDS dest semantics: wave-uniform base + lane*16.
__device__ __forceinline__ void gload_lds16(const void* g, void* l) {
  __builtin_amdgcn_global_load_lds(
      (const __attribute__((address_space(1))) unsigned int*)(uintptr_t)g,
      (__attribute__((address_space(3))) unsigned int*)(uintptr_t)l,
      16, 0, 0);
}

#define MFMA16(a, b, c) __builtin_amdgcn_mfma_f32_16x16x32_bf16((a), (b), (c), 0, 0, 0)

// ---------------- fp32 -> bf16 weight conversion ----------------------------
__global__ __launch_bounds__(256) void k_f2b(const float* __restrict__ src,
                                             ushort* __restrict__ dst, int n) {
  int i = blockIdx.x * 256 + threadIdx.x;
  if (i < n) dst[i] = f2bf(src[i]);
}

// ---------------- LayerNorm: fp32 in, bf16 out (+ optional shift+window) ----
template<bool WINDOW>
__global__ __launch_bounds__(256) void k_ln(const float* __restrict__ X,
    const float* __restrict__ G, const float* __restrict__ Bb,
    ushort* __restrict__ out)
{
  int token = blockIdx.x * 4 + (threadIdx.x >> 6);
  int lane  = threadIdx.x & 63;
  const float* xp = X + (size_t)token * C_;
  float v[6];
#pragma unroll
  for (int t = 0; t < 6; t++) v[t] = xp[lane + 64*t];
  float s = 0.f, s2 = 0.f;
#pragma unroll
  for (int t = 0; t < 6; t++) { s += v[t]; s2 += v[t]*v[t]; }
#pragma unroll
  for (int off = 32; off > 0; off >>= 1) {
    s  += __shfl_down(s,  off, 64);
    s2 += __shfl_down(s2, off, 64);
  }
  s = __shfl(s, 0, 64); s2 = __shfl(s2, 0, 64);
  float mu   = s * (1.f / C_);
  float rstd = rsqrtf(s2 * (1.f / C_) - mu * mu + 1e-5f);
  size_t obase;
  if (WINDOW) {
    int b = token / L_, pix = token % L_;
    int hi = pix / IMG, wj = pix % IMG;
    int sh = hi - 3; if (sh < 0) sh += IMG;
    int sw = wj - 3; if (sw < 0) sw += IMG;
    int w = b * NWIN + (sh / WS_) * 8 + (sw / WS_);
    int p = (sh % WS_) * WS_ + (sw % WS_);
    obase = ((size_t)w * N_ + p) * C_;
  } else {
    obase = (size_t)token * C_;
  }
#pragma unroll
  for (int t = 0; t < 6; t++) {
    int c = lane + 64*t;
    out[obase + c] = f2bf((v[t] - mu) * rstd * G[c] + Bb[c]);
  }
}

// ---------------- GEMM v2: B-resident-LDS, A-direct-to-register -------------
// C[M,N] = A[M,K] @ W[N,K]^T + bias.  BM=256 (wave owns 64 rows), BN=128.
// Rationale (R3 post-mortem): the old 64x64-wave-tile LDS-staged loop moved
// 48KB of LDS traffic per 78 MFMA-cycles -> structurally LDS-BW-bound (~22%
// MfmaUtil all rounds). Here W is tiny: stage B[128][128] in LDS ONCE per
// 128-col K-chunk (32KB), read A fragments directly global->VGPR (A has no
// intra-wave reuse; L2 serves re-reads across n-panels, T1 keeps panels of
// one m-tile on one XCD). Main-loop LDS traffic: 8KB/wave/K-step of B reads
// only (256B/MFMA). Barriers: 2 per chunk (4 K-steps), not per step.
// B LDS swizzle (row stride 256B = real 16-way conflict): physical colgroup
// cg holds logical cg^(row&7); applied on the GLOBAL source (rule #21,
// gload_lds dest stays linear), read with the same XOR.
// EPI: 0 bias (bf16 out); 1 bias+window-reverse scatter+fp32 residual (fp32
// out); 2 bias+gelu (bf16 out); 3 bias+fp32 residual row-aligned (fp32 out).
template<int EPI, typename OutT, int K>
__global__ __launch_bounds__(256, 2) void k_gemm2(
    const ushort* __restrict__ A, const ushort* __restrict__ W,
    const float* __restrict__ bias, OutT* __restrict__ out,
    const float* __restrict__ res, int M, int N)
{
  __shared__ __align__(16) ushort Bs[128*128];   // 32KB
  constexpr int NCH = K / 128;                   // chunks of 128 K-cols
  int ntn = N >> 7;
  int nwg = gridDim.x;
  int bid = (blockIdx.x & 7) * (nwg >> 3) + (blockIdx.x >> 3);   // T1 swizzle
  int m0 = (bid / ntn) << 8;
  int n0 = (bid % ntn) << 7;
  int tid  = threadIdx.x;
  int wave = tid >> 6, lane = tid & 63;
  int l15  = lane & 15, quad = lane >> 4;
  int wm = wave << 6;

  // ---- B staging addressing (8 gload_lds16 per thread per chunk) ----
  int srow = (wave << 2) + (lane >> 4);          // rows advance +16 per it
  int scg  = l15 ^ (srow & 7);                   // pre-swizzled global colgroup
  const ushort* gB = W + (size_t)(n0 + srow) * K + scg * 8;
  ushort* lB = &Bs[srow * 128 + l15 * 8];        // == wave-uniform + lane*16

  // ---- A fragment addressing: af[i] row = m0+wm+i*16+l15, cols k+quad*8 ----
  const ushort* gA = A + (size_t)(m0 + wm + l15) * K + quad * 8;

  f32x4 acc[4][8];
#pragma unroll
  for (int i = 0; i < 4; i++)
#pragma unroll
    for (int j = 0; j < 8; j++) acc[i][j] = (f32x4){0.f, 0.f, 0.f, 0.f};

  // ---- prologue: stage chunk 0, prefetch A step 0 ----
#pragma unroll
  for (int it = 0; it < 8; it++)
    gload_lds16(gB + (size_t)it * 16 * K, lB + it * 2048);
  bf16x8 afc[4], afn[4];
#pragma unroll
  for (int i = 0; i < 4; i++)
    afc[i] = *(const bf16x8*)(gA + (size_t)i * 16 * K);
  asm volatile("s_waitcnt vmcnt(0)" ::: "memory");
  __builtin_amdgcn_s_barrier();

  const ushort* gAn = gA + 32;          // next-step A pointer
  const ushort* gBk = gB;               // current chunk B pointer

  for (int ch = 0; ch < NCH; ch++) {
#pragma unroll
    for (int ss = 0; ss < 4; ss++) {
      bool last = (ch == NCH - 1) && (ss == 3);
      if (!last) {
#pragma unroll
        for (int i = 0; i < 4; i++)
          afn[i] = *(const bf16x8*)(gAn + (size_t)i * 16 * K);
        gAn += 32;
      }
      // compute step: B rows j*16+l15, chunk-local cols ss*32 + quad*8
#pragma unroll
      for (int j = 0; j < 8; j++) {
        int row = j * 16 + l15;
        int cg  = (ss * 4 + quad) ^ (row & 7);
        bf16x8 b = *(const bf16x8*)&Bs[row * 128 + cg * 8];
#pragma unroll
        for (int i = 0; i < 4; i++)
          acc[i][j] = MFMA16(afc[i], b, acc[i][j]);
      }
      if (ss == 3 && ch + 1 < NCH) {
        __builtin_amdgcn_s_barrier();   // all waves done reading this chunk
        gBk += 128;
#pragma unroll
        for (int it = 0; it < 8; it++)
          gload_lds16(gBk + (size_t)it * 16 * K, lB + it * 2048);
        asm volatile("s_waitcnt vmcnt(0)" ::: "memory");
        __builtin_amdgcn_s_barrier();
      }
      if (!last) {
#pragma unroll
        for (int i = 0; i < 4; i++) afc[i] = afn[i];
      }
    }
  }

  // ---- epilogue ----
  float bv[8];
#pragma unroll
  for (int j = 0; j < 8; j++) bv[j] = bias[n0 + j*16 + l15];
#pragma unroll
  for (int i = 0; i < 4; i++) {
#pragma unroll
    for (int r = 0; r < 4; r++) {
      int row = m0 + wm + i*16 + quad*4 + r;   // C/D layout: row=quad*4+reg, col=lane&15
      size_t dstbase;
      if (EPI == 1) {
        int w = row / N_, p = row % N_;
        int b = w >> 6, wi = w & 63;
        int hi = (wi >> 3) * WS_ + p / WS_ + 3; if (hi >= IMG) hi -= IMG;
        int wj = (wi & 7)  * WS_ + p % WS_ + 3; if (wj >= IMG) wj -= IMG;
        dstbase = ((size_t)b * L_ + hi * IMG + wj) * C_;
      } else {
        dstbase = (size_t)row * N;
      }
#pragma unroll
      for (int j = 0; j < 8; j++) {
        int col = n0 + j*16 + l15;
        float v = acc[i][j][r] + bv[j];
        if (EPI == 2) {
          // gelu(v) = v * sigmoid(1.5957691*(v + 0.044715 v^3))
          v = v / (1.f + __expf(-1.5957691216057308f * (v + 0.044715f * v * v * v)));
        }
        size_t dst = dstbase + col;
        if (EPI == 1) v += res[dst];
        if (EPI == 3) v += res[(size_t)row * N + col];
        if constexpr (sizeof(OutT) == 4) out[dst] = v;
        else                             out[dst] = f2bf(v);
      }
    }
  }
}

// ---------------- fused bias+mask precompute --------------------------------
__global__ __launch_bounds__(256) void k_bm(const float* __restrict__ relb,
    const float* __restrict__ mask, ushort* __restrict__ bm)
{
  int n = blockIdx.x * 256 + threadIdx.x;       // 64*12*4096 total
  int r    = n & 3;
  int col  = (n >> 2) & 63;
  int quad = (n >> 8) & 3;
  int i    = (n >> 10) & 3;
  int hw   = n >> 12;
  int h = hw % HEADS_, wc = hw / HEADS_;
  int row = i * 16 + quad * 4 + r;
  float v;
  if (col >= N_) v = -30000.f;
  else if (row >= N_) v = 0.f;
  else {
    int idx = (row / WS_ - col / WS_ + 6) * 13 + (row % WS_ - col % WS_ + 6);
    v = relb[idx * HEADS_ + h] + mask[((size_t)wc * N_ + row) * N_ + col];
  }
  bm[n] = f2bf(v);
}

// ---------------- MFMA windowed attention -----------------------------------
__global__ __launch_bounds__(256, 3) void k_attn_mfma(
    const ushort* __restrict__ qkv, const ushort* __restrict__ bm,
    ushort* __restrict__ out)
{
  __shared__ __align__(16) ushort Ps[4][64*64];   // 8KB/wave
  __shared__ __align__(16) ushort Vt[4][32*64];   // 4KB/wave
  int wave = threadIdx.x >> 6, lane = threadIdx.x & 63;
  int task = blockIdx.x * 4 + wave;
  int w = task / HEADS_, h = task % HEADS_;
  int l15 = lane & 15, quad = lane >> 4;

  const ushort* base = qkv + (size_t)w * N_ * QKVF + h * HD;

  // ---- Q/K fragments (rows clamped to 48; padding handled by bm/-30000) ----
  bf16x8 qf[4], kf[4];
#pragma unroll
  for (int i = 0; i < 4; i++) {
    int rr = i * 16 + l15; if (rr > 48) rr = 48;
    const ushort* rp = base + (size_t)rr * QKVF + quad * 8;
    qf[i] = *(const bf16x8*)rp;
    kf[i] = *(const bf16x8*)(rp + C_);
  }

  // ---- stage V^T into LDS (swizzled: ushort idx ^= (d&7)<<3) ----
  {
    int m = lane > 48 ? 48 : lane;
    const ushort* vp = base + (size_t)m * QKVF + 2 * C_;
    bf16x8 v0 = *(const bf16x8*)vp;
    bf16x8 v1 = *(const bf16x8*)(vp + 8);
    bf16x8 v2 = *(const bf16x8*)(vp + 16);
    bf16x8 v3 = *(const bf16x8*)(vp + 24);
    ushort* vt = &Vt[wave][0];
#pragma unroll
    for (int d = 0; d < 32; d++) {
      ushort val = (ushort)(d < 8 ? v0[d & 7] : d < 16 ? v1[d & 7]
                                  : d < 24 ? v2[d & 7] : v3[d & 7]);
      vt[d * 64 + (lane ^ ((d & 7) << 3))] = val;
    }
  }

  // ---- QK^T: 16 MFMAs, single K-step (HD=32) ----
  f32x4 acc[4][4];
#pragma unroll
  for (int i = 0; i < 4; i++)
#pragma unroll
    for (int j = 0; j < 4; j++) acc[i][j] = (f32x4){0.f, 0.f, 0.f, 0.f};
#pragma unroll
  for (int i = 0; i < 4; i++)
#pragma unroll
    for (int j = 0; j < 4; j++)
      acc[i][j] = MFMA16(qf[i], kf[j], acc[i][j]);

  // ---- scores: scale + fused bias/mask (pre-swizzled layout, ushort4/lane) ----
  const ushort* bmb = bm + ((size_t)(w & 63) * HEADS_ + h) * 4096;
  float sv[4][4][4];
#pragma unroll
  for (int i = 0; i < 4; i++)
#pragma unroll
    for (int j = 0; j < 4; j++) {
      u16x4 bv = *(const u16x4*)(bmb + (((i * 4 + quad) * 64) + (j * 16 + l15)) * 4);
#pragma unroll
      for (int r = 0; r < 4; r++)
        sv[i][j][r] = acc[i][j][r] * 0.17677669529663687f + bf2f(bv[r]);
    }

  // ---- wave-parallel softmax (rows live in (quad,r), cols in (j,l15)) ----
  float mx[4][4], sm[4][4];
#pragma unroll
  for (int i = 0; i < 4; i++)
#pragma unroll
    for (int r = 0; r < 4; r++)
      mx[i][r] = fmaxf(fmaxf(sv[i][0][r], sv[i][1][r]),
                       fmaxf(sv[i][2][r], sv[i][3][r]));
#pragma unroll
  for (int off = 1; off <= 8; off <<= 1)
#pragma unroll
    for (int i = 0; i < 4; i++)
#pragma unroll
      for (int r = 0; r < 4; r++)
        mx[i][r] = fmaxf(mx[i][r], __shfl_xor(mx[i][r], off, 64));
#pragma unroll
  for (int i = 0; i < 4; i++)
#pragma unroll
    for (int r = 0; r < 4; r++) sm[i][r] = 0.f;
#pragma unroll
  for (int i = 0; i < 4; i++)
#pragma unroll
    for (int j = 0; j < 4; j++)
#pragma unroll
      for (int r = 0; r < 4; r++) {
        float e = __expf(sv[i][j][r] - mx[i][r]);
        sv[i][j][r] = e;
        sm[i][r] += e;
      }
#pragma unroll
  for (int off = 1; off <= 8; off <<= 1)
#pragma unroll
    for (int i = 0; i < 4; i++)
#pragma unroll
      for (int r = 0; r < 4; r++)
        sm[i][r] += __shfl_xor(sm[i][r], off, 64);

  // ---- P (normalized, bf16) -> LDS, XOR-swizzled ----
  ushort* pw = &Ps[wave][0];
#pragma unroll
  for (int i = 0; i < 4; i++)
#pragma unroll
    for (int r = 0; r < 4; r++) {
      float inv = 1.f / sm[i][r];
      int row = i * 16 + quad * 4 + r;
      int s = (row & 7) << 3;
#pragma unroll
      for (int j = 0; j < 4; j++)
        pw[row * 64 + ((j * 16 + l15) ^ s)] = f2bf(sv[i][j][r] * inv);
    }

  // ---- PV: O[64x32] = P[64x64] @ V[64x32], 16 MFMAs ----
  f32x4 o[4][2];
#pragma unroll
  for (int i = 0; i < 4; i++)
#pragma unroll
    for (int jv = 0; jv < 2; jv++) o[i][jv] = (f32x4){0.f, 0.f, 0.f, 0.f};
  const ushort* vt = &Vt[wave][0];
#pragma unroll
  for (int ks = 0; ks < 2; ks++) {
    int kc = ks * 32 + quad * 8;
    bf16x8 pa[4], vb[2];
#pragma unroll
    for (int i = 0; i < 4; i++) {
      int row = i * 16 + l15;
      pa[i] = *(const bf16x8*)&pw[row * 64 + (kc ^ ((row & 7) << 3))];
    }
#pragma unroll
    for (int jv = 0; jv < 2; jv++) {
      int nn = jv * 16 + l15;
      vb[jv] = *(const bf16x8*)&vt[nn * 64 + (kc ^ ((nn & 7) << 3))];
    }
#pragma unroll
    for (int i = 0; i < 4; i++)
#pragma unroll
      for (int jv = 0; jv < 2; jv++)
        o[i][jv] = MFMA16(pa[i], vb[jv], o[i][jv]);
  }

  // ---- write O (valid rows only) ----
  ushort* op = out + ((size_t)w * N_) * C_ + h * HD;
#pragma unroll
  for (int i = 0; i < 4; i++)
#pragma unroll
    for (int r = 0; r < 4; r++) {
      int row = i * 16 + quad * 4 + r;
      if (row < N_) {
#pragma unroll
        for (int jv = 0; jv < 2; jv++)
          op[(size_t)row * C_ + jv * 16 + l15] = f2bf(o[i][jv][r]);
      }
    }
}

// ---------------------------------------------------------------------------
extern "C" void kernel_launch(void* const* d_in, const int* in_sizes, int n_in,
                              void* d_out, int out_size, void* d_ws, size_t ws_size,
                              hipStream_t stream) {
  (void)in_sizes; (void)n_in; (void)out_size; (void)ws_size;
  const float* x      = (const float*)d_in[0];
  const float* mask   = (const float*)d_in[1];
  const float* w_ln1  = (const float*)d_in[2];
  const float* b_ln1  = (const float*)d_in[3];
  const float* w_qkv  = (const float*)d_in[4];
  const float* b_qkv  = (const float*)d_in[5];
  const float* relb   = (const float*)d_in[6];
  const float* w_proj = (const float*)d_in[7];
  const float* b_proj = (const float*)d_in[8];
  const float* w_ln2  = (const float*)d_in[9];
  const float* b_ln2  = (const float*)d_in[10];
  const float* w_fc1  = (const float*)d_in[11];
  const float* b_fc1  = (const float*)d_in[12];
  const float* w_fc2  = (const float*)d_in[13];
  const float* b_fc2  = (const float*)d_in[14];

  // ws (bf16 internals):
  //   r0 [0, 308,281,344)                  qkv (231MB) -> mlp hidden (308MB)
  //      bm lives in r0 slack [231,211,008, +6,291,456) during attention
  //   r1 [308,281,344, +77,070,336)        hw -> attn_out -> h2
  //   wb [385,351,680, +3,538,944)         bf16 weights: qkv|proj|fc1|fc2
  // total = 388,890,624 B. x1 lives in d_out (fp32).
  char* ws = (char*)d_ws;
  ushort* r0 = (ushort*)ws;
  ushort* r1 = (ushort*)(ws + 308281344);
  ushort* bmt = (ushort*)(ws + 231211008);
  ushort* wbq = (ushort*)(ws + 385351680);
  ushort* wbp = wbq + QKVF * C_;          // 442368
  ushort* wb1 = wbp + C_ * C_;            // +147456
  ushort* wb2 = wb1 + 1536 * C_;          // +589824
  float*  x1   = (float*)d_out;
  float*  outp = (float*)d_out;

  k_f2b<<<(QKVF*C_ + 255)/256, 256, 0, stream>>>(w_qkv,  wbq, QKVF*C_);
  k_f2b<<<(C_*C_   + 255)/256, 256, 0, stream>>>(w_proj, wbp, C_*C_);
  k_f2b<<<(1536*C_ + 255)/256, 256, 0, stream>>>(w_fc1,  wb1, 1536*C_);
  k_f2b<<<(C_*1536 + 255)/256, 256, 0, stream>>>(w_fc2,  wb2, C_*1536);
  k_bm<<<(NWIN*HEADS_*4096)/256, 256, 0, stream>>>(relb, mask, bmt);

  k_ln<true ><<<M_TOK/4, 256, 0, stream>>>(x, w_ln1, b_ln1, r1);                 // r1 = hw
  k_gemm2<0, ushort, 384><<<(M_TOK/256)*(QKVF/128), 256, 0, stream>>>(
      r1, wbq, b_qkv, r0, nullptr, M_TOK, QKVF);                                 // r0 = qkv
  k_attn_mfma<<<NB*HEADS_/4, 256, 0, stream>>>(r0, bmt, r1);                     // r1 = attn_out
  k_gemm2<1, float, 384><<<(M_TOK/256)*(C_/128), 256, 0, stream>>>(
      r1, wbp, b_proj, x1, x, M_TOK, C_);                                        // x1 = x + o (fp32)
  k_ln<false><<<M_TOK/4, 256, 0, stream>>>(x1, w_ln2, b_ln2, r1);                // r1 = h2
  k_gemm2<2, ushort, 384><<<(M_TOK/256)*(1536/128), 256, 0, stream>>>(
      r1, wb1, b_fc1, r0, nullptr, M_TOK, 1536);                                 // r0 = hidden
  k_gemm2<3, float, 1536><<<(M_TOK/256)*(C_/128), 256, 0, stream>>>(
      r0, wb2, b_fc2, outp, x1, M_TOK, C_);                                      // out (fp32)
}

// Round 5
// 1028.682 us; speedup vs baseline: 1.2849x; 1.2849x over previous
//
#include <hip/hip_runtime.h>
#include <stdint.h>

#define B_     32
#define IMG    56
#define L_     (IMG*IMG)     // 3136
#define C_     384
#define HEADS_ 12
#define HD     32
#define WS_    7
#define N_     49
#define NWIN   64            // 8x8 windows per image
#define NB     (B_*NWIN)     // 2048
#define M_TOK  (NB*N_)       // 100352
#define QKVF   1152

typedef __attribute__((ext_vector_type(8))) short bf16x8;
typedef __attribute__((ext_vector_type(4))) float f32x4;
typedef __attribute__((ext_vector_type(4))) unsigned short u16x4;

__device__ __forceinline__ float bf2f(unsigned short u) {
  union { unsigned int u; float f; } c; c.u = ((unsigned int)u) << 16; return c.f;
}
__device__ __forceinline__ unsigned short f2bf(float f) {
  union { float f; unsigned int u; } c; c.f = f;
  unsigned int r = c.u + 0x7FFFu + ((c.u >> 16) & 1u);
  return (unsigned short)(r >> 16);
}

// async global->LDS, 16B per lane. LDS dest semantics: wave-uniform base + lane*16.
__device__ __forceinline__ void gload_lds16(const void* g, void* l) {
  __builtin_amdgcn_global_load_lds(
      (const __attribute__((address_space(1))) unsigned int*)(uintptr_t)g,
      (__attribute__((address_space(3))) unsigned int*)(uintptr_t)l,
      16, 0, 0);
}

#define MFMA16(a, b, c) __builtin_amdgcn_mfma_f32_16x16x32_bf16((a), (b), (c), 0, 0, 0)

// ---------------- merged setup: weight f2b x4 + bias/mask table -------------
// One launch instead of five. Index ranges:
//   [0, 442368)            wbq  <- w_qkv
//   [442368, 589824)       wbp  <- w_proj
//   [589824, 1179648)      wb1  <- w_fc1
//   [1179648, 1769472)     wb2  <- w_fc2
//   [1769472, 4915200)     bm   (64*12*4096 fused rel-bias + shift-mask)
__global__ __launch_bounds__(256) void k_prep(
    const float* __restrict__ w_qkv, const float* __restrict__ w_proj,
    const float* __restrict__ w_fc1, const float* __restrict__ w_fc2,
    const float* __restrict__ relb,  const float* __restrict__ mask,
    ushort* __restrict__ wbq, ushort* __restrict__ wbp,
    ushort* __restrict__ wb1, ushort* __restrict__ wb2,
    ushort* __restrict__ bm)
{
  int g = blockIdx.x * 256 + threadIdx.x;
  if (g < 442368)        { wbq[g]            = f2bf(w_qkv[g]); return; }
  if (g < 589824)        { wbp[g - 442368]   = f2bf(w_proj[g - 442368]); return; }
  if (g < 1179648)       { wb1[g - 589824]   = f2bf(w_fc1[g - 589824]); return; }
  if (g < 1769472)       { wb2[g - 1179648]  = f2bf(w_fc2[g - 1179648]); return; }
  int n = g - 1769472;   // bm[wc][h][i][quad][col][r], MFMA C-layout order
  int r    = n & 3;
  int col  = (n >> 2) & 63;
  int quad = (n >> 8) & 3;
  int i    = (n >> 10) & 3;
  int hw   = n >> 12;
  int h = hw % HEADS_, wc = hw / HEADS_;
  int row = i * 16 + quad * 4 + r;
  float v;
  if (col >= N_) v = -30000.f;
  else if (row >= N_) v = 0.f;
  else {
    int idx = (row / WS_ - col / WS_ + 6) * 13 + (row % WS_ - col % WS_ + 6);
    v = relb[idx * HEADS_ + h] + mask[((size_t)wc * N_ + row) * N_ + col];
  }
  bm[n] = f2bf(v);
}

// ---------------- LayerNorm: fp32 in, bf16 out (+ optional shift+window) ----
template<bool WINDOW>
__global__ __launch_bounds__(256) void k_ln(const float* __restrict__ X,
    const float* __restrict__ G, const float* __restrict__ Bb,
    ushort* __restrict__ out)
{
  int token = blockIdx.x * 4 + (threadIdx.x >> 6);
  int lane  = threadIdx.x & 63;
  const float* xp = X + (size_t)token * C_;
  float v[6];
#pragma unroll
  for (int t = 0; t < 6; t++) v[t] = xp[lane + 64*t];
  float s = 0.f, s2 = 0.f;
#pragma unroll
  for (int t = 0; t < 6; t++) { s += v[t]; s2 += v[t]*v[t]; }
#pragma unroll
  for (int off = 32; off > 0; off >>= 1) {
    s  += __shfl_down(s,  off, 64);
    s2 += __shfl_down(s2, off, 64);
  }
  s = __shfl(s, 0, 64); s2 = __shfl(s2, 0, 64);
  float mu   = s * (1.f / C_);
  float rstd = rsqrtf(s2 * (1.f / C_) - mu * mu + 1e-5f);
  size_t obase;
  if (WINDOW) {
    int b = token / L_, pix = token % L_;
    int hi = pix / IMG, wj = pix % IMG;
    int sh = hi - 3; if (sh < 0) sh += IMG;
    int sw = wj - 3; if (sw < 0) sw += IMG;
    int w = b * NWIN + (sh / WS_) * 8 + (sw / WS_);
    int p = (sh % WS_) * WS_ + (sw % WS_);
    obase = ((size_t)w * N_ + p) * C_;
  } else {
    obase = (size_t)token * C_;
  }
#pragma unroll
  for (int t = 0; t < 6; t++) {
    int c = lane + 64*t;
    out[obase + c] = f2bf((v[t] - mu) * rstd * G[c] + Bb[c]);
  }
}

// ---------------- GEMM: C[M,N] = A[M,K] @ W[N,K]^T + bias -------------------
// A, W bf16; bias fp32. 128x128 tile, BK=32, 4 waves, 4x4 MFMAs.
// 2-phase double-buffer (R2 structure, best measured): issue next-tile
// global_load_lds BEFORE current compute; vmcnt(0)+__syncthreads per K-step.
// Model note (R2-R4 calibration): LDS aggregate BW (~128 B/cy/CU) bounds this
// structure at ~21% MfmaUtil (48KB LDS traffic per 78 MFMA-cy block-step);
// scheduling/swizzle variants are neutral. SQ_LDS_BANK_CONFLICT ~= 4x b128
// read count = inherent wave64 multi-pass, not actionable.
// T1 XCD swizzle: consecutive logical tiles (sharing A) pinned to one XCD.
// EPI: 0 = bias only (bf16 out); 1 = bias + window-reverse scatter + fp32
// residual (fp32 out); 2 = bias + gelu (bf16 out); 3 = bias + fp32 residual
// row-aligned, in-place ok (fp32 out).
template<int EPI, typename OutT>
__global__ __launch_bounds__(256, 2) void k_gemm(
    const ushort* __restrict__ A, const ushort* __restrict__ W,
    const float* __restrict__ bias, OutT* __restrict__ out,
    const float* __restrict__ res, int M, int N, int K)
{
  __shared__ __align__(16) ushort As[2][128*32];
  __shared__ __align__(16) ushort Bs[2][128*32];
  int ntn = N >> 7;
  // T1: all our grids are multiples of 8 -> simple bijective XCD swizzle
  int nwg = gridDim.x;
  int bid = (blockIdx.x & 7) * (nwg >> 3) + (blockIdx.x >> 3);
  int m0 = (bid / ntn) << 7;
  int n0 = (bid % ntn) << 7;
  int tid  = threadIdx.x;
  int wave = tid >> 6, lane = tid & 63;
  int l15  = lane & 15, quad = lane >> 4;
  int wm = (wave & 1) << 6, wn = (wave >> 1) << 6;

  int srow0 = wave * 32 + (lane >> 2);
  int srow1 = srow0 + 16;
  int scol  = (lane & 3) * 8;
  const ushort* gA0 = A + (size_t)(m0 + srow0) * K + scol;
  const ushort* gA1 = A + (size_t)(m0 + srow1) * K + scol;
  const ushort* gB0 = W + (size_t)(n0 + srow0) * K + scol;
  const ushort* gB1 = W + (size_t)(n0 + srow1) * K + scol;
  int oA0 = srow0 * 32 + scol;
  int oA1 = srow1 * 32 + scol;

  f32x4 acc[4][4];
#pragma unroll
  for (int i = 0; i < 4; i++)
#pragma unroll
    for (int j = 0; j < 4; j++) acc[i][j] = (f32x4){0.f, 0.f, 0.f, 0.f};

  // prologue: stage tile 0 into buffer 0
  gload_lds16(gA0, &As[0][oA0]);
  gload_lds16(gA1, &As[0][oA1]);
  gload_lds16(gB0, &Bs[0][oA0]);
  gload_lds16(gB1, &Bs[0][oA1]);
  gA0 += 32; gA1 += 32; gB0 += 32; gB1 += 32;
  asm volatile("s_waitcnt vmcnt(0)" : : : "memory");
  __syncthreads();

  int nt = K >> 5;
  int cur = 0;
  for (int t = 0; t < nt; t++) {
    int nxt = cur ^ 1;
    if (t + 1 < nt) {
      // issue next-tile loads first: they complete under this tile's MFMAs
      gload_lds16(gA0, &As[nxt][oA0]);
      gload_lds16(gA1, &As[nxt][oA1]);
      gload_lds16(gB0, &Bs[nxt][oA0]);
      gload_lds16(gB1, &Bs[nxt][oA1]);
      gA0 += 32; gA1 += 32; gB0 += 32; gB1 += 32;
    }
    bf16x8 af[4], bfr[4];
#pragma unroll
    for (int i = 0; i < 4; i++) af[i]  = *(const bf16x8*)&As[cur][(wm + i*16 + l15)*32 + quad*8];
#pragma unroll
    for (int j = 0; j < 4; j++) bfr[j] = *(const bf16x8*)&Bs[cur][(wn + j*16 + l15)*32 + quad*8];
#pragma unroll
    for (int i = 0; i < 4; i++)
#pragma unroll
      for (int j = 0; j < 4; j++)
        acc[i][j] = MFMA16(af[i], bfr[j], acc[i][j]);
    asm volatile("s_waitcnt vmcnt(0)" : : : "memory");
    __syncthreads();
    cur = nxt;
  }

  float bv[4];
#pragma unroll
  for (int j = 0; j < 4; j++) bv[j] = bias[n0 + wn + j*16 + l15];
#pragma unroll
  for (int i = 0; i < 4; i++) {
#pragma unroll
    for (int r = 0; r < 4; r++) {
      int row = m0 + wm + i*16 + quad*4 + r;   // C/D layout: row=quad*4+reg, col=lane&15
      size_t dstbase;
      if (EPI == 1) {
        int w = row / N_, p = row % N_;
        int b = w >> 6, wi = w & 63;
        int hi = (wi >> 3) * WS_ + p / WS_ + 3; if (hi >= IMG) hi -= IMG;
        int wj = (wi & 7)  * WS_ + p % WS_ + 3; if (wj >= IMG) wj -= IMG;
        dstbase = ((size_t)b * L_ + hi * IMG + wj) * C_;
      } else {
        dstbase = (size_t)row * N;
      }
#pragma unroll
      for (int j = 0; j < 4; j++) {
        int col = n0 + wn + j*16 + l15;
        float v = acc[i][j][r] + bv[j];
        if (EPI == 2) {
          // gelu(v) = v * sigmoid(1.5957691*(v + 0.044715 v^3)); fast rcp
          float e = __expf(-1.5957691216057308f * (v + 0.044715f * v * v * v));
          v = v * __builtin_amdgcn_rcpf(1.f + e);
        }
        size_t dst = dstbase + col;
        if (EPI == 1) v += res[dst];
        if (EPI == 3) v += res[(size_t)row * N + col];
        if constexpr (sizeof(OutT) == 4) out[dst] = v;
        else                             out[dst] = f2bf(v);
      }
    }
  }
}

// ---------------- MFMA windowed attention -----------------------------------
// One wave per (window, head). 49 padded to 64 (4x4 tiles of 16x16x32).
// QK^T: A=Q frag, B=K frag (B=K^T so both are contiguous row reads).
// Softmax wave-parallel in C-layout (row reduce = 3 fmax + 4 shfl_xor).
// P (bf16, /rowsum folded) -> LDS XOR-swizzled; V^T staged to LDS swizzled
// so PV B-frag is a contiguous swizzled ds_read_b128. No __syncthreads:
// LDS regions are wave-private.
__global__ __launch_bounds__(256, 3) void k_attn_mfma(
    const ushort* __restrict__ qkv, const ushort* __restrict__ bm,
    ushort* __restrict__ out)
{
  __shared__ __align__(16) ushort Ps[4][64*64];   // 8KB/wave
  __shared__ __align__(16) ushort Vt[4][32*64];   // 4KB/wave
  int wave = threadIdx.x >> 6, lane = threadIdx.x & 63;
  int task = blockIdx.x * 4 + wave;
  int w = task / HEADS_, h = task % HEADS_;
  int l15 = lane & 15, quad = lane >> 4;

  const ushort* base = qkv + (size_t)w * N_ * QKVF + h * HD;

  // ---- Q/K fragments (rows clamped to 48; padding handled by bm/-30000) ----
  bf16x8 qf[4], kf[4];
#pragma unroll
  for (int i = 0; i < 4; i++) {
    int rr = i * 16 + l15; if (rr > 48) rr = 48;
    const ushort* rp = base + (size_t)rr * QKVF + quad * 8;
    qf[i] = *(const bf16x8*)rp;
    kf[i] = *(const bf16x8*)(rp + C_);
  }

  // ---- stage V^T into LDS (swizzled: ushort idx ^= (d&7)<<3) ----
  {
    int m = lane > 48 ? 48 : lane;
    const ushort* vp = base + (size_t)m * QKVF + 2 * C_;
    bf16x8 v0 = *(const bf16x8*)vp;
    bf16x8 v1 = *(const bf16x8*)(vp + 8);
    bf16x8 v2 = *(const bf16x8*)(vp + 16);
    bf16x8 v3 = *(const bf16x8*)(vp + 24);
    ushort* vt = &Vt[wave][0];
#pragma unroll
    for (int d = 0; d < 32; d++) {
      ushort val = (ushort)(d < 8 ? v0[d & 7] : d < 16 ? v1[d & 7]
                                  : d < 24 ? v2[d & 7] : v3[d & 7]);
      vt[d * 64 + (lane ^ ((d & 7) << 3))] = val;
    }
  }

  // ---- QK^T: 16 MFMAs, single K-step (HD=32) ----
  f32x4 acc[4][4];
#pragma unroll
  for (int i = 0; i < 4; i++)
#pragma unroll
    for (int j = 0; j < 4; j++) acc[i][j] = (f32x4){0.f, 0.f, 0.f, 0.f};
#pragma unroll
  for (int i = 0; i < 4; i++)
#pragma unroll
    for (int j = 0; j < 4; j++)
      acc[i][j] = MFMA16(qf[i], kf[j], acc[i][j]);

  // ---- scores: scale + fused bias/mask (pre-swizzled layout, ushort4/lane) ----
  const ushort* bmb = bm + ((size_t)(w & 63) * HEADS_ + h) * 4096;
  float sv[4][4][4];
#pragma unroll
  for (int i = 0; i < 4; i++)
#pragma unroll
    for (int j = 0; j < 4; j++) {
      u16x4 bv = *(const u16x4*)(bmb + (((i * 4 + quad) * 64) + (j * 16 + l15)) * 4);
#pragma unroll
      for (int r = 0; r < 4; r++)
        sv[i][j][r] = acc[i][j][r] * 0.17677669529663687f + bf2f(bv[r]);
    }

  // ---- wave-parallel softmax (rows live in (quad,r), cols in (j,l15)) ----
  float mx[4][4], sm[4][4];
#pragma unroll
  for (int i = 0; i < 4; i++)
#pragma unroll
    for (int r = 0; r < 4; r++)
      mx[i][r] = fmaxf(fmaxf(sv[i][0][r], sv[i][1][r]),
                       fmaxf(sv[i][2][r], sv[i][3][r]));
#pragma unroll
  for (int off = 1; off <= 8; off <<= 1)
#pragma unroll
    for (int i = 0; i < 4; i++)
#pragma unroll
      for (int r = 0; r < 4; r++)
        mx[i][r] = fmaxf(mx[i][r], __shfl_xor(mx[i][r], off, 64));
#pragma unroll
  for (int i = 0; i < 4; i++)
#pragma unroll
    for (int r = 0; r < 4; r++) sm[i][r] = 0.f;
#pragma unroll
  for (int i = 0; i < 4; i++)
#pragma unroll
    for (int j = 0; j < 4; j++)
#pragma unroll
      for (int r = 0; r < 4; r++) {
        float e = __expf(sv[i][j][r] - mx[i][r]);
        sv[i][j][r] = e;
        sm[i][r] += e;
      }
#pragma unroll
  for (int off = 1; off <= 8; off <<= 1)
#pragma unroll
    for (int i = 0; i < 4; i++)
#pragma unroll
      for (int r = 0; r < 4; r++)
        sm[i][r] += __shfl_xor(sm[i][r], off, 64);

  // ---- P (normalized, bf16) -> LDS, XOR-swizzled ----
  ushort* pw = &Ps[wave][0];
#pragma unroll
  for (int i = 0; i < 4; i++)
#pragma unroll
    for (int r = 0; r < 4; r++) {
      float inv = __builtin_amdgcn_rcpf(sm[i][r]);
      int row = i * 16 + quad * 4 + r;
      int s = (row & 7) << 3;
#pragma unroll
      for (int j = 0; j < 4; j++)
        pw[row * 64 + ((j * 16 + l15) ^ s)] = f2bf(sv[i][j][r] * inv);
    }

  // ---- PV: O[64x32] = P[64x64] @ V[64x32], 16 MFMAs ----
  f32x4 o[4][2];
#pragma unroll
  for (int i = 0; i < 4; i++)
#pragma unroll
    for (int jv = 0; jv < 2; jv++) o[i][jv] = (f32x4){0.f, 0.f, 0.f, 0.f};
  const ushort* vt = &Vt[wave][0];
#pragma unroll
  for (int ks = 0; ks < 2; ks++) {
    int kc = ks * 32 + quad * 8;
    bf16x8 pa[4], vb[2];
#pragma unroll
    for (int i = 0; i < 4; i++) {
      int row = i * 16 + l15;
      pa[i] = *(const bf16x8*)&pw[row * 64 + (kc ^ ((row & 7) << 3))];
    }
#pragma unroll
    for (int jv = 0; jv < 2; jv++) {
      int nn = jv * 16 + l15;
      vb[jv] = *(const bf16x8*)&vt[nn * 64 + (kc ^ ((nn & 7) << 3))];
    }
#pragma unroll
    for (int i = 0; i < 4; i++)
#pragma unroll
      for (int jv = 0; jv < 2; jv++)
        o[i][jv] = MFMA16(pa[i], vb[jv], o[i][jv]);
  }

  // ---- write O (valid rows only) ----
  ushort* op = out + ((size_t)w * N_) * C_ + h * HD;
#pragma unroll
  for (int i = 0; i < 4; i++)
#pragma unroll
    for (int r = 0; r < 4; r++) {
      int row = i * 16 + quad * 4 + r;
      if (row < N_) {
#pragma unroll
        for (int jv = 0; jv < 2; jv++)
          op[(size_t)row * C_ + jv * 16 + l15] = f2bf(o[i][jv][r]);
      }
    }
}

// ---------------------------------------------------------------------------
extern "C" void kernel_launch(void* const* d_in, const int* in_sizes, int n_in,
                              void* d_out, int out_size, void* d_ws, size_t ws_size,
                              hipStream_t stream) {
  (void)in_sizes; (void)n_in; (void)out_size; (void)ws_size;
  const float* x      = (const float*)d_in[0];
  const float* mask   = (const float*)d_in[1];
  const float* w_ln1  = (const float*)d_in[2];
  const float* b_ln1  = (const float*)d_in[3];
  const float* w_qkv  = (const float*)d_in[4];
  const float* b_qkv  = (const float*)d_in[5];
  const float* relb   = (const float*)d_in[6];
  const float* w_proj = (const float*)d_in[7];
  const float* b_proj = (const float*)d_in[8];
  const float* w_ln2  = (const float*)d_in[9];
  const float* b_ln2  = (const float*)d_in[10];
  const float* w_fc1  = (const float*)d_in[11];
  const float* b_fc1  = (const float*)d_in[12];
  const float* w_fc2  = (const float*)d_in[13];
  const float* b_fc2  = (const float*)d_in[14];

  // ws (bf16 internals):
  //   r0 [0, 308,281,344)                  qkv (231MB) -> mlp hidden (308MB)
  //      bm lives in r0 slack [231,211,008, +6,291,456) during attention
  //   r1 [308,281,344, +77,070,336)        hw -> attn_out -> h2
  //   wb [385,351,680, +3,538,944)         bf16 weights: qkv|proj|fc1|fc2
  // total = 388,890,624 B. x1 lives in d_out (fp32).
  char* ws = (char*)d_ws;
  ushort* r0 = (ushort*)ws;
  ushort* r1 = (ushort*)(ws + 308281344);
  ushort* bmt = (ushort*)(ws + 231211008);
  ushort* wbq = (ushort*)(ws + 385351680);
  ushort* wbp = wbq + QKVF * C_;          // 442368
  ushort* wb1 = wbp + C_ * C_;            // +147456
  ushort* wb2 = wb1 + 1536 * C_;          // +589824
  float*  x1   = (float*)d_out;
  float*  outp = (float*)d_out;

  // merged setup: 4 weight conversions + bias/mask table in one launch
  k_prep<<<4915200/256, 256, 0, stream>>>(w_qkv, w_proj, w_fc1, w_fc2,
                                          relb, mask, wbq, wbp, wb1, wb2, bmt);

  k_ln<true ><<<M_TOK/4, 256, 0, stream>>>(x, w_ln1, b_ln1, r1);                 // r1 = hw
  k_gemm<0, ushort><<<(M_TOK/128)*(QKVF/128), 256, 0, stream>>>(
      r1, wbq, b_qkv, r0, nullptr, M_TOK, QKVF, 384);                            // r0 = qkv
  k_attn_mfma<<<NB*HEADS_/4, 256, 0, stream>>>(r0, bmt, r1);                     // r1 = attn_out
  k_gemm<1, float><<<(M_TOK/128)*(C_/128), 256, 0, stream>>>(
      r1, wbp, b_proj, x1, x, M_TOK, C_, 384);                                   // x1 = x + o (fp32)
  k_ln<false><<<M_TOK/4, 256, 0, stream>>>(x1, w_ln2, b_ln2, r1);                // r1 = h2
  k_gemm<2, ushort><<<(M_TOK/128)*(1536/128), 256, 0, stream>>>(
      r1, wb1, b_fc1, r0, nullptr, M_TOK, 1536, 384);                            // r0 = hidden
  k_gemm<3, float><<<(M_TOK/128)*(C_/128), 256, 0, stream>>>(
      r0, wb2, b_fc2, outp, x1, M_TOK, C_, 1536);                                // out (fp32)
}

// Round 6
// 1003.981 us; speedup vs baseline: 1.3165x; 1.0246x over previous
//
#include <hip/hip_runtime.h>
#include <stdint.h>

#define B_     32
#define IMG    56
#define L_     (IMG*IMG)     // 3136
#define C_     384
#define HEADS_ 12
#define HD     32
#define WS_    7
#define N_     49
#define NWIN   64            // 8x8 windows per image
#define NB     (B_*NWIN)     // 2048
#define M_TOK  (NB*N_)       // 100352
#define QKVF   1152

typedef __attribute__((ext_vector_type(8))) short bf16x8;
typedef __attribute__((ext_vector_type(4))) float f32x4;
typedef __attribute__((ext_vector_type(4))) unsigned short u16x4;

__device__ __forceinline__ float bf2f(unsigned short u) {
  union { unsigned int u; float f; } c; c.u = ((unsigned int)u) << 16; return c.f;
}
__device__ __forceinline__ unsigned short f2bf(float f) {
  union { float f; unsigned int u; } c; c.f = f;
  unsigned int r = c.u + 0x7FFFu + ((c.u >> 16) & 1u);
  return (unsigned short)(r >> 16);
}

// async global->LDS, 16B per lane. LDS dest semantics: wave-uniform base + lane*16.
__device__ __forceinline__ void gload_lds16(const void* g, void* l) {
  __builtin_amdgcn_global_load_lds(
      (const __attribute__((address_space(1))) unsigned int*)(uintptr_t)g,
      (__attribute__((address_space(3))) unsigned int*)(uintptr_t)l,
      16, 0, 0);
}

#define MFMA16(a, b, c) __builtin_amdgcn_mfma_f32_16x16x32_bf16((a), (b), (c), 0, 0, 0)

// ---------------- merged setup: weight f2b x4 + bias/mask table -------------
__global__ __launch_bounds__(256) void k_prep(
    const float* __restrict__ w_qkv, const float* __restrict__ w_proj,
    const float* __restrict__ w_fc1, const float* __restrict__ w_fc2,
    const float* __restrict__ relb,  const float* __restrict__ mask,
    ushort* __restrict__ wbq, ushort* __restrict__ wbp,
    ushort* __restrict__ wb1, ushort* __restrict__ wb2,
    ushort* __restrict__ bm)
{
  int g = blockIdx.x * 256 + threadIdx.x;
  if (g < 442368)        { wbq[g]            = f2bf(w_qkv[g]); return; }
  if (g < 589824)        { wbp[g - 442368]   = f2bf(w_proj[g - 442368]); return; }
  if (g < 1179648)       { wb1[g - 589824]   = f2bf(w_fc1[g - 589824]); return; }
  if (g < 1769472)       { wb2[g - 1179648]  = f2bf(w_fc2[g - 1179648]); return; }
  int n = g - 1769472;   // bm[wc][h][i][quad][col][r], MFMA C-layout order
  int r    = n & 3;
  int col  = (n >> 2) & 63;
  int quad = (n >> 8) & 3;
  int i    = (n >> 10) & 3;
  int hw   = n >> 12;
  int h = hw % HEADS_, wc = hw / HEADS_;
  int row = i * 16 + quad * 4 + r;
  float v;
  if (col >= N_) v = -30000.f;
  else if (row >= N_) v = 0.f;
  else {
    int idx = (row / WS_ - col / WS_ + 6) * 13 + (row % WS_ - col % WS_ + 6);
    v = relb[idx * HEADS_ + h] + mask[((size_t)wc * N_ + row) * N_ + col];
  }
  bm[n] = f2bf(v);
}

// ---------------- LayerNorm: fp32 in, bf16 out (+ optional shift+window) ----
template<bool WINDOW>
__global__ __launch_bounds__(256) void k_ln(const float* __restrict__ X,
    const float* __restrict__ G, const float* __restrict__ Bb,
    ushort* __restrict__ out)
{
  int token = blockIdx.x * 4 + (threadIdx.x >> 6);
  int lane  = threadIdx.x & 63;
  const float* xp = X + (size_t)token * C_;
  float v[6];
#pragma unroll
  for (int t = 0; t < 6; t++) v[t] = xp[lane + 64*t];
  float s = 0.f, s2 = 0.f;
#pragma unroll
  for (int t = 0; t < 6; t++) { s += v[t]; s2 += v[t]*v[t]; }
#pragma unroll
  for (int off = 32; off > 0; off >>= 1) {
    s  += __shfl_down(s,  off, 64);
    s2 += __shfl_down(s2, off, 64);
  }
  s = __shfl(s, 0, 64); s2 = __shfl(s2, 0, 64);
  float mu   = s * (1.f / C_);
  float rstd = rsqrtf(s2 * (1.f / C_) - mu * mu + 1e-5f);
  size_t obase;
  if (WINDOW) {
    int b = token / L_, pix = token % L_;
    int hi = pix / IMG, wj = pix % IMG;
    int sh = hi - 3; if (sh < 0) sh += IMG;
    int sw = wj - 3; if (sw < 0) sw += IMG;
    int w = b * NWIN + (sh / WS_) * 8 + (sw / WS_);
    int p = (sh % WS_) * WS_ + (sw % WS_);
    obase = ((size_t)w * N_ + p) * C_;
  } else {
    obase = (size_t)token * C_;
  }
#pragma unroll
  for (int t = 0; t < 6; t++) {
    int c = lane + 64*t;
    out[obase + c] = f2bf((v[t] - mu) * rstd * G[c] + Bb[c]);
  }
}

// ---------------- GEMM: C[M,N] = A[M,K] @ W[N,K]^T + bias -------------------
// A, W bf16; bias fp32. R6 geometry: BM=256 x BN=128 tile, BK=32, 4 waves
// (2m x 2n), wave-tile 128x64, acc[8][4]. Rationale (R5 calibration): the old
// 64x64 wave-tile read 512 B LDS per MFMA -> LDS-read-BW-bound at ~23%
// MfmaUtil across ALL scheduling variants. 128x64 reads 12KB per 32 MFMAs =
// 375 B/MFMA; per-CU balance: ~376cy LDS reads vs ~310cy MFMA per K-step ->
// ~45% potential. Same proven 2-phase dbuf (issue-early, drain-late) and T1
// XCD swizzle. 48KB LDS dbuf; ~200 VGPR -> 2 blocks/CU.
// EPI: 0 = bias only (bf16 out); 1 = bias + window-reverse scatter + fp32
// residual (fp32 out); 2 = bias + gelu (bf16 out); 3 = bias + fp32 residual
// row-aligned, in-place ok (fp32 out).
template<int EPI, typename OutT>
__global__ __launch_bounds__(256, 2) void k_gemm(
    const ushort* __restrict__ A, const ushort* __restrict__ W,
    const float* __restrict__ bias, OutT* __restrict__ out,
    const float* __restrict__ res, int M, int N, int K)
{
  __shared__ __align__(16) ushort As[2][256*32];   // 32KB
  __shared__ __align__(16) ushort Bs[2][128*32];   // 16KB
  int ntn = N >> 7;
  // T1: all our grids are multiples of 8 -> simple bijective XCD swizzle
  int nwg = gridDim.x;
  int bid = (blockIdx.x & 7) * (nwg >> 3) + (blockIdx.x >> 3);
  int m0 = (bid / ntn) << 8;
  int n0 = (bid % ntn) << 7;
  int tid  = threadIdx.x;
  int wave = tid >> 6, lane = tid & 63;
  int l15  = lane & 15, quad = lane >> 4;
  int wm = (wave >> 1) << 7;   // 0 / 128
  int wn = (wave & 1) << 6;    // 0 / 64

  // staging: per thread 4 A-rounds + 2 B-rounds of 16B (rows advance +64/round)
  int srow = tid >> 2;              // 0..63
  int scol = (tid & 3) * 8;
  const ushort* gA = A + (size_t)(m0 + srow) * K + scol;
  const ushort* gB = W + (size_t)(n0 + srow) * K + scol;
  int oA = srow * 32 + scol;

  f32x4 acc[8][4];
#pragma unroll
  for (int i = 0; i < 8; i++)
#pragma unroll
    for (int j = 0; j < 4; j++) acc[i][j] = (f32x4){0.f, 0.f, 0.f, 0.f};

  // prologue: stage tile 0 into buffer 0
#pragma unroll
  for (int it = 0; it < 4; it++)
    gload_lds16(gA + (size_t)it * 64 * K, &As[0][oA + it * 2048]);
#pragma unroll
  for (int it = 0; it < 2; it++)
    gload_lds16(gB + (size_t)it * 64 * K, &Bs[0][oA + it * 2048]);
  gA += 32; gB += 32;
  asm volatile("s_waitcnt vmcnt(0)" : : : "memory");
  __syncthreads();

  int nt = K >> 5;
  int cur = 0;
  for (int t = 0; t < nt; t++) {
    int nxt = cur ^ 1;
    if (t + 1 < nt) {
      // issue next-tile loads first: they complete under this tile's MFMAs
#pragma unroll
      for (int it = 0; it < 4; it++)
        gload_lds16(gA + (size_t)it * 64 * K, &As[nxt][oA + it * 2048]);
#pragma unroll
      for (int it = 0; it < 2; it++)
        gload_lds16(gB + (size_t)it * 64 * K, &Bs[nxt][oA + it * 2048]);
      gA += 32; gB += 32;
    }
    bf16x8 af[8], bfr[4];
#pragma unroll
    for (int i = 0; i < 8; i++) af[i]  = *(const bf16x8*)&As[cur][(wm + i*16 + l15)*32 + quad*8];
#pragma unroll
    for (int j = 0; j < 4; j++) bfr[j] = *(const bf16x8*)&Bs[cur][(wn + j*16 + l15)*32 + quad*8];
#pragma unroll
    for (int i = 0; i < 8; i++)
#pragma unroll
      for (int j = 0; j < 4; j++)
        acc[i][j] = MFMA16(af[i], bfr[j], acc[i][j]);
    asm volatile("s_waitcnt vmcnt(0)" : : : "memory");
    __syncthreads();
    cur = nxt;
  }

  float bv[4];
#pragma unroll
  for (int j = 0; j < 4; j++) bv[j] = bias[n0 + wn + j*16 + l15];
#pragma unroll
  for (int i = 0; i < 8; i++) {
#pragma unroll
    for (int r = 0; r < 4; r++) {
      int row = m0 + wm + i*16 + quad*4 + r;   // C/D layout: row=quad*4+reg, col=lane&15
      size_t dstbase;
      if (EPI == 1) {
        int w = row / N_, p = row % N_;
        int b = w >> 6, wi = w & 63;
        int hi = (wi >> 3) * WS_ + p / WS_ + 3; if (hi >= IMG) hi -= IMG;
        int wj = (wi & 7)  * WS_ + p % WS_ + 3; if (wj >= IMG) wj -= IMG;
        dstbase = ((size_t)b * L_ + hi * IMG + wj) * C_;
      } else {
        dstbase = (size_t)row * N;
      }
#pragma unroll
      for (int j = 0; j < 4; j++) {
        int col = n0 + wn + j*16 + l15;
        float v = acc[i][j][r] + bv[j];
        if (EPI == 2) {
          // gelu(v) = v * sigmoid(1.5957691*(v + 0.044715 v^3)); fast rcp
          float e = __expf(-1.5957691216057308f * (v + 0.044715f * v * v * v));
          v = v * __builtin_amdgcn_rcpf(1.f + e);
        }
        size_t dst = dstbase + col;
        if (EPI == 1) v += res[dst];
        if (EPI == 3) v += res[(size_t)row * N + col];
        if constexpr (sizeof(OutT) == 4) out[dst] = v;
        else                             out[dst] = f2bf(v);
      }
    }
  }
}

// ---------------- MFMA windowed attention -----------------------------------
__global__ __launch_bounds__(256, 3) void k_attn_mfma(
    const ushort* __restrict__ qkv, const ushort* __restrict__ bm,
    ushort* __restrict__ out)
{
  __shared__ __align__(16) ushort Ps[4][64*64];   // 8KB/wave
  __shared__ __align__(16) ushort Vt[4][32*64];   // 4KB/wave
  int wave = threadIdx.x >> 6, lane = threadIdx.x & 63;
  int task = blockIdx.x * 4 + wave;
  int w = task / HEADS_, h = task % HEADS_;
  int l15 = lane & 15, quad = lane >> 4;

  const ushort* base = qkv + (size_t)w * N_ * QKVF + h * HD;

  // ---- Q/K fragments (rows clamped to 48; padding handled by bm/-30000) ----
  bf16x8 qf[4], kf[4];
#pragma unroll
  for (int i = 0; i < 4; i++) {
    int rr = i * 16 + l15; if (rr > 48) rr = 48;
    const ushort* rp = base + (size_t)rr * QKVF + quad * 8;
    qf[i] = *(const bf16x8*)rp;
    kf[i] = *(const bf16x8*)(rp + C_);
  }

  // ---- stage V^T into LDS (swizzled: ushort idx ^= (d&7)<<3) ----
  {
    int m = lane > 48 ? 48 : lane;
    const ushort* vp = base + (size_t)m * QKVF + 2 * C_;
    bf16x8 v0 = *(const bf16x8*)vp;
    bf16x8 v1 = *(const bf16x8*)(vp + 8);
    bf16x8 v2 = *(const bf16x8*)(vp + 16);
    bf16x8 v3 = *(const bf16x8*)(vp + 24);
    ushort* vt = &Vt[wave][0];
#pragma unroll
    for (int d = 0; d < 32; d++) {
      ushort val = (ushort)(d < 8 ? v0[d & 7] : d < 16 ? v1[d & 7]
                                  : d < 24 ? v2[d & 7] : v3[d & 7]);
      vt[d * 64 + (lane ^ ((d & 7) << 3))] = val;
    }
  }

  // ---- QK^T: 16 MFMAs, single K-step (HD=32) ----
  f32x4 acc[4][4];
#pragma unroll
  for (int i = 0; i < 4; i++)
#pragma unroll
    for (int j = 0; j < 4; j++) acc[i][j] = (f32x4){0.f, 0.f, 0.f, 0.f};
#pragma unroll
  for (int i = 0; i < 4; i++)
#pragma unroll
    for (int j = 0; j < 4; j++)
      acc[i][j] = MFMA16(qf[i], kf[j], acc[i][j]);

  // ---- scores: scale + fused bias/mask (pre-swizzled layout, ushort4/lane) ----
  const ushort* bmb = bm + ((size_t)(w & 63) * HEADS_ + h) * 4096;
  float sv[4][4][4];
#pragma unroll
  for (int i = 0; i < 4; i++)
#pragma unroll
    for (int j = 0; j < 4; j++) {
      u16x4 bv = *(const u16x4*)(bmb + (((i * 4 + quad) * 64) + (j * 16 + l15)) * 4);
#pragma unroll
      for (int r = 0; r < 4; r++)
        sv[i][j][r] = acc[i][j][r] * 0.17677669529663687f + bf2f(bv[r]);
    }

  // ---- wave-parallel softmax (rows live in (quad,r), cols in (j,l15)) ----
  float mx[4][4], sm[4][4];
#pragma unroll
  for (int i = 0; i < 4; i++)
#pragma unroll
    for (int r = 0; r < 4; r++)
      mx[i][r] = fmaxf(fmaxf(sv[i][0][r], sv[i][1][r]),
                       fmaxf(sv[i][2][r], sv[i][3][r]));
#pragma unroll
  for (int off = 1; off <= 8; off <<= 1)
#pragma unroll
    for (int i = 0; i < 4; i++)
#pragma unroll
      for (int r = 0; r < 4; r++)
        mx[i][r] = fmaxf(mx[i][r], __shfl_xor(mx[i][r], off, 64));
#pragma unroll
  for (int i = 0; i < 4; i++)
#pragma unroll
    for (int r = 0; r < 4; r++) sm[i][r] = 0.f;
#pragma unroll
  for (int i = 0; i < 4; i++)
#pragma unroll
    for (int j = 0; j < 4; j++)
#pragma unroll
      for (int r = 0; r < 4; r++) {
        float e = __expf(sv[i][j][r] - mx[i][r]);
        sv[i][j][r] = e;
        sm[i][r] += e;
      }
#pragma unroll
  for (int off = 1; off <= 8; off <<= 1)
#pragma unroll
    for (int i = 0; i < 4; i++)
#pragma unroll
      for (int r = 0; r < 4; r++)
        sm[i][r] += __shfl_xor(sm[i][r], off, 64);

  // ---- P (normalized, bf16) -> LDS, XOR-swizzled ----
  ushort* pw = &Ps[wave][0];
#pragma unroll
  for (int i = 0; i < 4; i++)
#pragma unroll
    for (int r = 0; r < 4; r++) {
      float inv = __builtin_amdgcn_rcpf(sm[i][r]);
      int row = i * 16 + quad * 4 + r;
      int s = (row & 7) << 3;
#pragma unroll
      for (int j = 0; j < 4; j++)
        pw[row * 64 + ((j * 16 + l15) ^ s)] = f2bf(sv[i][j][r] * inv);
    }

  // ---- PV: O[64x32] = P[64x64] @ V[64x32], 16 MFMAs ----
  f32x4 o[4][2];
#pragma unroll
  for (int i = 0; i < 4; i++)
#pragma unroll
    for (int jv = 0; jv < 2; jv++) o[i][jv] = (f32x4){0.f, 0.f, 0.f, 0.f};
  const ushort* vt = &Vt[wave][0];
#pragma unroll
  for (int ks = 0; ks < 2; ks++) {
    int kc = ks * 32 + quad * 8;
    bf16x8 pa[4], vb[2];
#pragma unroll
    for (int i = 0; i < 4; i++) {
      int row = i * 16 + l15;
      pa[i] = *(const bf16x8*)&pw[row * 64 + (kc ^ ((row & 7) << 3))];
    }
#pragma unroll
    for (int jv = 0; jv < 2; jv++) {
      int nn = jv * 16 + l15;
      vb[jv] = *(const bf16x8*)&vt[nn * 64 + (kc ^ ((nn & 7) << 3))];
    }
#pragma unroll
    for (int i = 0; i < 4; i++)
#pragma unroll
      for (int jv = 0; jv < 2; jv++)
        o[i][jv] = MFMA16(pa[i], vb[jv], o[i][jv]);
  }

  // ---- write O (valid rows only) ----
  ushort* op = out + ((size_t)w * N_) * C_ + h * HD;
#pragma unroll
  for (int i = 0; i < 4; i++)
#pragma unroll
    for (int r = 0; r < 4; r++) {
      int row = i * 16 + quad * 4 + r;
      if (row < N_) {
#pragma unroll
        for (int jv = 0; jv < 2; jv++)
          op[(size_t)row * C_ + jv * 16 + l15] = f2bf(o[i][jv][r]);
      }
    }
}

// ---------------------------------------------------------------------------
extern "C" void kernel_launch(void* const* d_in, const int* in_sizes, int n_in,
                              void* d_out, int out_size, void* d_ws, size_t ws_size,
                              hipStream_t stream) {
  (void)in_sizes; (void)n_in; (void)out_size; (void)ws_size;
  const float* x      = (const float*)d_in[0];
  const float* mask   = (const float*)d_in[1];
  const float* w_ln1  = (const float*)d_in[2];
  const float* b_ln1  = (const float*)d_in[3];
  const float* w_qkv  = (const float*)d_in[4];
  const float* b_qkv  = (const float*)d_in[5];
  const float* relb   = (const float*)d_in[6];
  const float* w_proj = (const float*)d_in[7];
  const float* b_proj = (const float*)d_in[8];
  const float* w_ln2  = (const float*)d_in[9];
  const float* b_ln2  = (const float*)d_in[10];
  const float* w_fc1  = (const float*)d_in[11];
  const float* b_fc1  = (const float*)d_in[12];
  const float* w_fc2  = (const float*)d_in[13];
  const float* b_fc2  = (const float*)d_in[14];

  // ws (bf16 internals):
  //   r0 [0, 308,281,344)                  qkv (231MB) -> mlp hidden (308MB)
  //      bm lives in r0 slack [231,211,008, +6,291,456) during attention
  //   r1 [308,281,344, +77,070,336)        hw -> attn_out -> h2
  //   wb [385,351,680, +3,538,944)         bf16 weights: qkv|proj|fc1|fc2
  // total = 388,890,624 B. x1 lives in d_out (fp32).
  char* ws = (char*)d_ws;
  ushort* r0 = (ushort*)ws;
  ushort* r1 = (ushort*)(ws + 308281344);
  ushort* bmt = (ushort*)(ws + 231211008);
  ushort* wbq = (ushort*)(ws + 385351680);
  ushort* wbp = wbq + QKVF * C_;          // 442368
  ushort* wb1 = wbp + C_ * C_;            // +147456
  ushort* wb2 = wb1 + 1536 * C_;          // +589824
  float*  x1   = (float*)d_out;
  float*  outp = (float*)d_out;

  // merged setup: 4 weight conversions + bias/mask table in one launch
  k_prep<<<4915200/256, 256, 0, stream>>>(w_qkv, w_proj, w_fc1, w_fc2,
                                          relb, mask, wbq, wbp, wb1, wb2, bmt);

  k_ln<true ><<<M_TOK/4, 256, 0, stream>>>(x, w_ln1, b_ln1, r1);                 // r1 = hw
  k_gemm<0, ushort><<<(M_TOK/256)*(QKVF/128), 256, 0, stream>>>(
      r1, wbq, b_qkv, r0, nullptr, M_TOK, QKVF, 384);                            // r0 = qkv
  k_attn_mfma<<<NB*HEADS_/4, 256, 0, stream>>>(r0, bmt, r1);                     // r1 = attn_out
  k_gemm<1, float><<<(M_TOK/256)*(C_/128), 256, 0, stream>>>(
      r1, wbp, b_proj, x1, x, M_TOK, C_, 384);                                   // x1 = x + o (fp32)
  k_ln<false><<<M_TOK/4, 256, 0, stream>>>(x1, w_ln2, b_ln2, r1);                // r1 = h2
  k_gemm<2, ushort><<<(M_TOK/256)*(1536/128), 256, 0, stream>>>(
      r1, wb1, b_fc1, r0, nullptr, M_TOK, 1536, 384);                            // r0 = hidden
  k_gemm<3, float><<<(M_TOK/256)*(C_/128), 256, 0, stream>>>(
      r0, wb2, b_fc2, outp, x1, M_TOK, C_, 1536);                                // out (fp32)
}